// Round 4
// baseline (184.995 us; speedup 1.0000x reference)
//
#include <hip/hip_runtime.h>
#include <math.h>

#define BB 64
#define NN 256
#define IN_F 128
#define OF 128
#define HH 4
#define NEG_SLOPE 0.2f

typedef __attribute__((ext_vector_type(8))) short short8;
typedef __attribute__((ext_vector_type(4))) float f32x4;

#define MFMA16(a, b, c) __builtin_amdgcn_mfma_f32_16x16x32_bf16(a, b, c, 0, 0, 0)

// float -> bf16 bits, round-to-nearest-even (finite)
__device__ inline unsigned short f2bf(float x) {
    unsigned u = __float_as_uint(x);
    u += 0x7fff + ((u >> 16) & 1);
    return (unsigned short)(u >> 16);
}

// ---------------- K0: conversions / transposes ----------------
// blocks [0,2048): h -> h_bf (bf16, same layout), coalesced
// blocks [2048,2056): W[128k][512f] -> Wt[512f][128k] bf16 (LDS transpose, 16 k-rows/block)
// blocks [2056,2088): Wc[512k][128c] -> Wct[128c][512k] bf16 (LDS transpose, 16 k-rows/block)
__global__ __launch_bounds__(256) void k0_convert(const float* __restrict__ h,
        const float* __restrict__ W, const float* __restrict__ Wc,
        unsigned short* __restrict__ h_bf, unsigned short* __restrict__ Wt,
        unsigned short* __restrict__ Wct) {
    __shared__ float hl[16][516];
    int blk = blockIdx.x, t = threadIdx.x;
    if (blk < 2048) {
        int idx = blk * 256 + t;                 // float4 index, 524288 total
        float4 v = ((const float4*)h)[idx];
        ushort4 o;
        o.x = f2bf(v.x); o.y = f2bf(v.y); o.z = f2bf(v.z); o.w = f2bf(v.w);
        ((ushort4*)h_bf)[idx] = o;
    } else if (blk < 2056) {
        int k0 = (blk - 2048) * 16;
#pragma unroll
        for (int it = 0; it < 8; it++) {         // stage 16x512 f32, coalesced
            int li = it * 256 + t;
            int row = li >> 7, col4 = li & 127;
            float4 v = ((const float4*)(W + (size_t)(k0 + row) * 512))[col4];
            *(float4*)&hl[row][col4 * 4] = v;
        }
        __syncthreads();
#pragma unroll
        for (int cc = 0; cc < 2; cc++) {         // write Wt rows: 32B contiguous per c
            int c = t * 2 + cc;
            short8 s0, s1;
#pragma unroll
            for (int k = 0; k < 8; k++) s0[k] = (short)f2bf(hl[k][c]);
#pragma unroll
            for (int k = 0; k < 8; k++) s1[k] = (short)f2bf(hl[k + 8][c]);
            unsigned short* dst = Wt + (size_t)c * 128 + k0;
            *(short8*)dst = s0;
            *(short8*)(dst + 8) = s1;
        }
    } else {
        int k0 = (blk - 2056) * 16;
#pragma unroll
        for (int it = 0; it < 2; it++) {         // stage 16x128 f32
            int li = it * 256 + t;
            int row = li >> 5, col4 = li & 31;
            float4 v = ((const float4*)(Wc + (size_t)(k0 + row) * 128))[col4];
            *(float4*)&hl[row][col4 * 4] = v;
        }
        __syncthreads();
        if (t < 128) {
            int c = t;
            short8 s0, s1;
#pragma unroll
            for (int k = 0; k < 8; k++) s0[k] = (short)f2bf(hl[k][c]);
#pragma unroll
            for (int k = 0; k < 8; k++) s1[k] = (short)f2bf(hl[k + 8][c]);
            unsigned short* dst = Wct + (size_t)c * 512 + k0;
            *(short8*)dst = s0;
            *(short8*)(dst + 8) = s1;
        }
    }
}

// ---------------- K1: Wht = (h@W)^T via MFMA + fp32 per-node scalars ----------
// grid = 256 (XCD-remapped: 4 n-chunks of b co-located), 4 waves, wave = head.
// Register-lean: acc[4] per tf iteration; scalar dots folded into tf loop.
__global__ __launch_bounds__(256) void k1_wh(const unsigned short* __restrict__ h_bf,
        const unsigned short* __restrict__ Wt, const float* __restrict__ a,
        const float* __restrict__ w_proj, const float* __restrict__ w_sim,
        unsigned short* __restrict__ Wht, float* __restrict__ ei,
        float* __restrict__ ej, float* __restrict__ sp, float* __restrict__ ss) {
    __shared__ float a1s[512], a2s[512], wps[128], wss[128];
    int l = blockIdx.x;
    int xcd = l & 7, m = l >> 3;
    int b = xcd + ((m >> 2) << 3);
    int n0 = (m & 3) * 64;
    int t = threadIdx.x;
    for (int idx = t; idx < 512; idx += 256) {
        int hh = idx >> 7, f = idx & 127;
        a1s[idx] = a[hh * 256 + f];
        a2s[idx] = a[hh * 256 + 128 + f];
    }
    if (t < 128) { wps[t] = w_proj[t]; wss[t] = w_sim[t]; }
    __syncthreads();

    int w = t >> 6, lane = t & 63;
    int cc = lane & 15, g = lane >> 4;

    // B-frags: h^T[k][n]; lane: col n = tn*16+cc, k = ks*32 + g*8 + e
    short8 bh[4][4];
#pragma unroll
    for (int tn = 0; tn < 4; tn++)
#pragma unroll
        for (int ks = 0; ks < 4; ks++)
            bh[tn][ks] = *(const short8*)(h_bf +
                ((size_t)(b * NN + n0 + tn * 16 + cc)) * IN_F + ks * 32 + g * 8);

    float q0[4] = {0.f,0.f,0.f,0.f}, q1[4] = {0.f,0.f,0.f,0.f};
    float q2[4] = {0.f,0.f,0.f,0.f}, q3[4] = {0.f,0.f,0.f,0.f};
    unsigned short* whb = Wht + (size_t)(b * HH + w) * OF * NN;

#pragma unroll
    for (int tf = 0; tf < 8; tf++) {
        short8 aw[4];   // A-frags: Wt[f][k], row f = w*128 + tf*16 + cc
#pragma unroll
        for (int ks = 0; ks < 4; ks++)
            aw[ks] = *(const short8*)(Wt +
                (size_t)(w * 128 + tf * 16 + cc) * IN_F + ks * 32 + g * 8);
        f32x4 acc[4];
#pragma unroll
        for (int tn = 0; tn < 4; tn++) acc[tn] = (f32x4)(0.f);
#pragma unroll
        for (int tn = 0; tn < 4; tn++)
#pragma unroll
            for (int ks = 0; ks < 4; ks++)
                acc[tn] = MFMA16(aw[ks], bh[tn][ks], acc[tn]);

        float a1v[4], a2v[4], wpv[4], wsv[4];
#pragma unroll
        for (int r = 0; r < 4; r++) {
            int f = tf * 16 + g * 4 + r;
            a1v[r] = a1s[w * 128 + f];
            a2v[r] = a2s[w * 128 + f];
            wpv[r] = wps[f];
            wsv[r] = wss[f];
        }
#pragma unroll
        for (int tn = 0; tn < 4; tn++)
#pragma unroll
            for (int r = 0; r < 4; r++) {
                float v = acc[tn][r];
                q0[tn] += v * a1v[r];
                q1[tn] += v * a2v[r];
                q2[tn] += v * wpv[r];
                q3[tn] += v * wsv[r];
                whb[(size_t)(tf * 16 + g * 4 + r) * NN + n0 + tn * 16 + cc] = f2bf(v);
            }
    }

#pragma unroll
    for (int tn = 0; tn < 4; tn++) {
        float p0 = q0[tn], p1 = q1[tn], p2 = q2[tn], p3 = q3[tn];
        p0 += __shfl_xor(p0, 16); p0 += __shfl_xor(p0, 32);
        p1 += __shfl_xor(p1, 16); p1 += __shfl_xor(p1, 32);
        p2 += __shfl_xor(p2, 16); p2 += __shfl_xor(p2, 32);
        p3 += __shfl_xor(p3, 16); p3 += __shfl_xor(p3, 32);
        if (g == 0) {
            size_t idx = (size_t)(b * HH + w) * NN + n0 + tn * 16 + cc;
            ei[idx] = p0; ej[idx] = p1; sp[idx] = p2; ss[idx] = p3;
        }
    }
}

// ---------------- K2: e + softmax (wave-per-row) + MFMA PV + MFMA Wc + ELU ----
__global__ __launch_bounds__(256) void k2_fused(
        const float* __restrict__ proj, const float* __restrict__ sim,
        const int* __restrict__ qm, const float* __restrict__ qbias,
        const float* __restrict__ ei, const float* __restrict__ ej,
        const float* __restrict__ sp, const float* __restrict__ ss,
        const unsigned short* __restrict__ Wht, const unsigned short* __restrict__ Wct,
        float* __restrict__ out) {
    __shared__ __align__(16) char at_lds[32768];   // attn bf16 [4][16][256], XOR-swizzled rows
    __shared__ __align__(16) char hp_lds[16384];   // union: ejs f32[4][256] / hp bf16[16][512] swizzled
    __shared__ float eis[HH][16], sps[HH][16], sss[HH][16];
    __shared__ float qb_s[16];
    float* ejs = (float*)hp_lds;

    int l = blockIdx.x;                  // XCD-bijective remap: chunks of b co-located
    int xcd = l & 7, m = l >> 3;
    int b = xcd + ((m >> 4) << 3);
    int i0 = (m & 15) * 16;
    int t = threadIdx.x;
    int wave = t >> 6, lane = t & 63;

    for (int c = t; c < HH * NN; c += 256)
        ejs[c] = ej[(size_t)b * HH * NN + c];
    if (t < 64) {
        int hh = t >> 4, ii = t & 15;
        size_t base = ((size_t)b * HH + hh) * NN + i0 + ii;
        eis[hh][ii] = ei[base]; sps[hh][ii] = sp[base]; sss[hh][ii] = ss[base];
    }
    if (t < 16) qb_s[t] = qbias[t];
    __syncthreads();

    // ---- phase B: wave owns rows wave*4..+3; lane owns j = lane*4..+3.
    // All 16 streaming loads issued up front for latency overlap.
    int j0 = lane * 4;
    float4 P4[4], S4[4];
    int4 qa[4], qc[4];
#pragma unroll
    for (int rr = 0; rr < 4; rr++) {
        int i = i0 + wave * 4 + rr;
        size_t rb = ((size_t)b * NN + i) * NN + j0;
        P4[rr] = *(const float4*)&proj[rb];
        S4[rr] = *(const float4*)&sim[rb];
        qa[rr] = *(const int4*)&qm[rb * 2];
        qc[rr] = *(const int4*)&qm[rb * 2 + 4];
    }
#pragma unroll
    for (int rr = 0; rr < 4; rr++) {
        int ii = wave * 4 + rr;
        float qb0 = qb_s[qa[rr].x * 4 + qa[rr].y], qb1 = qb_s[qa[rr].z * 4 + qa[rr].w];
        float qb2 = qb_s[qc[rr].x * 4 + qc[rr].y], qb3 = qb_s[qc[rr].z * 4 + qc[rr].w];
        float e[HH][4];
#pragma unroll
        for (int hh = 0; hh < HH; hh++) {
            float4 ej4 = *(const float4*)&ejs[hh * 256 + j0];
            float bi = eis[hh][ii], spv = sps[hh][ii], ssv = sss[hh][ii];
            float x;
            x = bi + ej4.x; x = x > 0.f ? x : NEG_SLOPE * x; e[hh][0] = x + spv * P4[rr].x + ssv * S4[rr].x + qb0;
            x = bi + ej4.y; x = x > 0.f ? x : NEG_SLOPE * x; e[hh][1] = x + spv * P4[rr].y + ssv * S4[rr].y + qb1;
            x = bi + ej4.z; x = x > 0.f ? x : NEG_SLOPE * x; e[hh][2] = x + spv * P4[rr].z + ssv * S4[rr].z + qb2;
            x = bi + ej4.w; x = x > 0.f ? x : NEG_SLOPE * x; e[hh][3] = x + spv * P4[rr].w + ssv * S4[rr].w + qb3;
        }
        float mx[HH];
#pragma unroll
        for (int hh = 0; hh < HH; hh++)
            mx[hh] = fmaxf(fmaxf(e[hh][0], e[hh][1]), fmaxf(e[hh][2], e[hh][3]));
#pragma unroll
        for (int off = 32; off; off >>= 1)
#pragma unroll
            for (int hh = 0; hh < HH; hh++)
                mx[hh] = fmaxf(mx[hh], __shfl_xor(mx[hh], off));
        float s[HH];
#pragma unroll
        for (int hh = 0; hh < HH; hh++) {
            e[hh][0] = __expf(e[hh][0] - mx[hh]);
            e[hh][1] = __expf(e[hh][1] - mx[hh]);
            e[hh][2] = __expf(e[hh][2] - mx[hh]);
            e[hh][3] = __expf(e[hh][3] - mx[hh]);
            s[hh] = (e[hh][0] + e[hh][1]) + (e[hh][2] + e[hh][3]);
        }
#pragma unroll
        for (int off = 32; off; off >>= 1)
#pragma unroll
            for (int hh = 0; hh < HH; hh++) s[hh] += __shfl_xor(s[hh], off);
#pragma unroll
        for (int hh = 0; hh < HH; hh++) {
            float inv = 1.0f / s[hh];
            ushort4 pk;
            pk.x = f2bf(e[hh][0] * inv);
            pk.y = f2bf(e[hh][1] * inv);
            pk.z = f2bf(e[hh][2] * inv);
            pk.w = f2bf(e[hh][3] * inv);
            int off2 = hh * 8192 + ii * 512 + ((j0 * 2) ^ ((ii & 7) << 4));
            *(ushort4*)(at_lds + off2) = pk;
        }
    }
    __syncthreads();

    // ---- phase C: per wave (head w): hp[16 x 128] = attn[16 x 256] @ Wh[256 x 128]
    int w = wave;
    int row = lane & 15, g = lane >> 4;
    short8 af[8];
#pragma unroll
    for (int ks = 0; ks < 8; ks++) {
        int off = w * 8192 + row * 512 + ((((ks * 32 + g * 8) * 2)) ^ ((row & 7) << 4));
        af[ks] = *(const short8*)(at_lds + off);
    }
    f32x4 acc[8];
#pragma unroll
    for (int ft = 0; ft < 8; ft++) acc[ft] = (f32x4)(0.f);
    const unsigned short* whb = Wht + (size_t)(b * HH + w) * OF * NN;
#pragma unroll
    for (int ft = 0; ft < 8; ft++) {
        const unsigned short* wb = whb + (size_t)(ft * 16 + row) * NN + g * 8;
#pragma unroll
        for (int ks = 0; ks < 8; ks++) {
            short8 bf = *(const short8*)(wb + ks * 32);
            acc[ft] = MFMA16(af[ks], bf, acc[ft]);
        }
    }
    // hp -> bf16 LDS (swizzled rows of 1024B); i = g*4+r, kf = w*128 + ft*16 + row
#pragma unroll
    for (int ft = 0; ft < 8; ft++)
#pragma unroll
        for (int r = 0; r < 4; r++) {
            int i = g * 4 + r;
            int kf = w * 128 + ft * 16 + row;
            int off = i * 1024 + ((kf * 2) ^ ((i & 7) << 4));
            *(unsigned short*)(hp_lds + off) = f2bf(acc[ft][r]);
        }
    __syncthreads();

    // ---- phase D: out[16 x 128] = elu(hp[16 x 512] @ Wc[512 x 128])
    short8 ah[16];
#pragma unroll
    for (int ks = 0; ks < 16; ks++) {
        int off = row * 1024 + (((ks * 32 + g * 8) * 2) ^ ((row & 7) << 4));
        ah[ks] = *(const short8*)(hp_lds + off);
    }
    f32x4 o2[2];
    o2[0] = (f32x4)(0.f); o2[1] = (f32x4)(0.f);
#pragma unroll
    for (int ct = 0; ct < 2; ct++) {
        int c = (w * 2 + ct) * 16 + row;
        const unsigned short* wc = Wct + (size_t)c * 512 + g * 8;
#pragma unroll
        for (int ks = 0; ks < 16; ks++) {
            short8 bf = *(const short8*)(wc + ks * 32);
            o2[ct] = MFMA16(ah[ks], bf, o2[ct]);
        }
    }
#pragma unroll
    for (int ct = 0; ct < 2; ct++)
#pragma unroll
        for (int r = 0; r < 4; r++) {
            float v = o2[ct][r];
            v = v > 0.f ? v : expm1f(v);
            int i = i0 + g * 4 + r;
            int c = (w * 2 + ct) * 16 + row;
            out[((size_t)b * NN + i) * OF + c] = v;
        }
}

extern "C" void kernel_launch(void* const* d_in, const int* in_sizes, int n_in,
                              void* d_out, int out_size, void* d_ws, size_t ws_size,
                              hipStream_t stream) {
    const float* h      = (const float*)d_in[0];
    const float* proj   = (const float*)d_in[1];
    const float* sim    = (const float*)d_in[2];
    const int*   qm     = (const int*)d_in[3];
    const float* W      = (const float*)d_in[4];
    const float* a      = (const float*)d_in[5];
    const float* w_proj = (const float*)d_in[6];
    const float* w_sim  = (const float*)d_in[7];
    const float* qbias  = (const float*)d_in[8];
    const float* Wc     = (const float*)d_in[9];
    float* out = (float*)d_out;

    unsigned short* h_bf = (unsigned short*)d_ws;              // 2,097,152
    unsigned short* Wt   = h_bf + (size_t)BB * NN * IN_F;      // 65,536
    unsigned short* Wct  = Wt + 512 * 128;                     // 65,536
    unsigned short* Wht  = Wct + 128 * 512;                    // 8,388,608
    float* ei = (float*)(Wht + (size_t)BB * HH * OF * NN);
    float* ej = ei + (size_t)BB * HH * NN;
    float* sp = ej + (size_t)BB * HH * NN;
    float* ss = sp + (size_t)BB * HH * NN;

    k0_convert<<<2088, 256, 0, stream>>>(h, W, Wc, h_bf, Wt, Wct);
    k1_wh<<<BB * 4, 256, 0, stream>>>(h_bf, Wt, a, w_proj, w_sim, Wht, ei, ej, sp, ss);
    k2_fused<<<BB * 16, 256, 0, stream>>>(proj, sim, qm, qbias, ei, ej, sp, ss, Wht, Wct, out);
}